// Round 16
// baseline (671.066 us; speedup 1.0000x reference)
//
#include <hip/hip_runtime.h>
#include <hip/hip_bf16.h>
#include <hip/hip_fp16.h>
#include <math.h>

// ---------------------------------------------------------------------------
// VDPWI forward. gemm_xw via fp16 hi/lo 3-term MFMA (frag-linear A), fp32
// LSTM (persistent v2p: packed-fp32 FMA inner loop), fused sim+greedy+focus,
// bf16 MFMA convs, fused conv5+dense. B=256, L=32, D=300, H=250, NLAB=5.
// ---------------------------------------------------------------------------

#define NEGV (-10000.0f)

typedef unsigned short u16;
typedef __attribute__((ext_vector_type(8))) short s8v;       // 8 bf16
typedef __attribute__((ext_vector_type(8))) _Float16 h8v;    // 8 fp16
typedef __attribute__((ext_vector_type(4))) float f4v;
typedef __attribute__((ext_vector_type(2))) float f2v;       // v_pk_fma_f32

// ---------------- prep: transpose_hl + wih_frag + repack_whh ----------------
__global__ __launch_bounds__(256) void prep_all(const float* __restrict__ sent1,
                                                const float* __restrict__ sent2,
                                                const float* __restrict__ Wih,
                                                const float* __restrict__ Whh,
                                                u16* __restrict__ Afh,
                                                u16* __restrict__ Afl,
                                                u16* __restrict__ wihf,
                                                float4* __restrict__ Wg4) {
  __shared__ float lds[300 * 33];
  const int blk = blockIdx.x;
  if (blk < 512) {
    int s = blk >> 8, b = blk & 255;
    const float* in = (s ? sent2 : sent1) + (size_t)b * 9600;   // [300][32]
    for (int idx = threadIdx.x; idx < 9600; idx += 256) {
      int d = idx >> 5, tt = idx & 31;
      lds[d * 33 + tt] = in[idx];
    }
    __syncthreads();
    for (int odx = threadIdx.x; odx < 32 * 320; odx += 256) {
      int tt = odx / 320, d = odx - (odx / 320) * 320;
      float v = (d < 300) ? lds[d * 33 + tt] : 0.f;
      _Float16 hi = (_Float16)v;
      _Float16 lo = (_Float16)(v - (float)hi);
      int i = (s << 13) + (tt << 8) + b;
      int rowblk = i >> 4, li = i & 15;
      int kg = d >> 5, g = (d & 31) >> 3, e = d & 7;
      size_t o = (((size_t)rowblk * 10 + kg) * 64 + (g * 16 + li)) * 8 + e;
      union { _Float16 f; u16 u; } c0, c1;
      c0.f = hi; c1.f = lo;
      Afh[o] = c0.u;
      Afl[o] = c1.u;
    }
  } else if (blk < 1792) {
    int id = (blk - 512) * 256 + threadIdx.x;     // < 327680
    if (id < 327680) {
      int e    = id & 7;
      int lane = (id >> 3) & 63;
      int nf   = (id >> 9) & 63;
      int kg   = id >> 15;
      int j = nf * 16 + (lane & 15);
      int k = kg * 32 + (lane >> 4) * 8 + e;
      float v = 0.f;
      if (j < 1000 && k < 300) v = Wih[(size_t)j * 300 + k];
      _Float16 hi = (_Float16)v;
      _Float16 lo = (_Float16)(v - (float)hi);
      size_t base = (((size_t)kg * 64 + nf) * 2 * 64 + lane) * 8 + e;
      union { _Float16 f; u16 u; } c0, c1;
      c0.f = hi; c1.f = lo;
      wihf[base]       = c0.u;
      wihf[base + 512] = c1.u;
    }
  } else {
    int idx = (blk - 1792) * 256 + threadIdx.x;   // k*250 + u < 62500
    if (idx < 62500) {
      int k = idx / 250, u = idx - k * 250;
      float4 v;
      v.x = Whh[(size_t)(u)       * 250 + k];
      v.y = Whh[(size_t)(250 + u) * 250 + k];
      v.z = Whh[(size_t)(500 + u) * 250 + k];
      v.w = Whh[(size_t)(750 + u) * 250 + k];
      Wg4[idx] = v;
    }
  }
}

// ---------------- xW GEMM via MFMA: [16384x320]x[320x1024] + bias ----------
__global__ __launch_bounds__(256) void gemm_xw_mfma(const u16* __restrict__ Afh,
                                                    const u16* __restrict__ Afl,
                                                    const u16* __restrict__ bf,
                                                    const float* __restrict__ bih,
                                                    const float* __restrict__ bhh,
                                                    float* __restrict__ xW) {
  const int tid = threadIdx.x;
  const int lane = tid & 63, w = tid >> 6;
  const int li = lane & 15, g = lane >> 4;
  const int i0 = blockIdx.x * 256;
  const int j0 = blockIdx.y * 64;
  const int rb0 = (i0 >> 4) + w * 4;          // rowblk base for this wave

  f4v acc[4][4];
#pragma unroll
  for (int f = 0; f < 4; f++)
#pragma unroll
    for (int n = 0; n < 4; n++) acc[f][n] = (f4v){0.f, 0.f, 0.f, 0.f};

#pragma unroll 1
  for (int kg = 0; kg < 10; kg++) {
    h8v ah[4], al[4];
#pragma unroll
    for (int f = 0; f < 4; f++) {
      size_t aoff = (((size_t)(rb0 + f) * 10 + kg) * 64 + lane) * 8;
      ah[f] = *(const h8v*)(Afh + aoff);
      al[f] = *(const h8v*)(Afl + aoff);
    }
    h8v bh[4], bl[4];
#pragma unroll
    for (int n = 0; n < 4; n++) {
      size_t boff = (((size_t)kg * 64 + (j0 >> 4) + n) * 2 * 64 + lane) * 8;
      bh[n] = *(const h8v*)(bf + boff);
      bl[n] = *(const h8v*)(bf + boff + 512);
    }
#pragma unroll
    for (int f = 0; f < 4; f++)
#pragma unroll
      for (int n = 0; n < 4; n++) {
        acc[f][n] = __builtin_amdgcn_mfma_f32_16x16x32_f16(ah[f], bh[n], acc[f][n], 0, 0, 0);
        acc[f][n] = __builtin_amdgcn_mfma_f32_16x16x32_f16(ah[f], bl[n], acc[f][n], 0, 0, 0);
        acc[f][n] = __builtin_amdgcn_mfma_f32_16x16x32_f16(al[f], bh[n], acc[f][n], 0, 0, 0);
      }
  }

  float bia[4];
#pragma unroll
  for (int n = 0; n < 4; n++) {
    int j = j0 + n * 16 + li;
    bia[n] = (j < 1000) ? (bih[j] + bhh[j]) : 0.f;
  }
#pragma unroll
  for (int f = 0; f < 4; f++)
#pragma unroll
    for (int n = 0; n < 4; n++) {
      int j = j0 + n * 16 + li;
      if (j < 1000) {
#pragma unroll
        for (int r = 0; r < 4; r++) {
          int i = i0 + w * 64 + f * 16 + g * 4 + r;
          xW[(size_t)i * 1000 + j] = acc[f][n][r] + bia[n];
        }
      }
    }
}

// ---------------- persistent LSTM v2p: packed-fp32 FMA inner loop ----------
// Identical structure to proven v2 (384us); inner 16 scalar FMA -> 8 f2v
// fma (v_pk_fma_f32 on CDNA). Accumulator aP[r]={gate i,f}, aQ[r]={gate g,o}.
__global__ __launch_bounds__(512, 1) void lstm_persist2p(const float4* __restrict__ Wg4,
                                                         const float* __restrict__ xW,
                                                         float* __restrict__ seq) {
  __shared__ float4 hs[256];
  __shared__ float asum[16][256];
  const int tid = threadIdx.x;
  const int u = tid & 255;
  const int kh = tid >> 8;
  const bool act = (u < 250);
  const int uu = act ? u : 249;
  const int i0 = blockIdx.x * 4;
  const int lset = i0 >> 8;
  const int s = lset >> 1, dir = lset & 1;

  float4 c = make_float4(0.f, 0.f, 0.f, 0.f);
  if (tid < 256) hs[tid] = make_float4(0.f, 0.f, 0.f, 0.f);
  __syncthreads();

  const float4* wp = Wg4 + uu;
  const int k0 = kh * 125;

  for (int t = 0; t < 32; t++) {
    const int tin = dir ? (31 - t) : t;

    float xv[16];
    if (kh == 0) {
      const float* xb = xW + ((size_t)(s * 32 + tin) * 256 + (i0 & 255)) * 1000 + uu;
#pragma unroll
      for (int r = 0; r < 4; r++)
#pragma unroll
        for (int q = 0; q < 4; q++)
          xv[r * 4 + q] = xb[r * 1000 + q * 250];
    }

    f2v aP0 = {0.f, 0.f}, aQ0 = aP0, aP1 = aP0, aQ1 = aP0;
    f2v aP2 = aP0, aQ2 = aP0, aP3 = aP0, aQ3 = aP0;
#pragma unroll 5
    for (int k = k0; k < k0 + 125; k++) {
      float4 w = wp[(size_t)k * 250];
      float4 h = hs[k];
      f2v wlo = {w.x, w.y}, whi = {w.z, w.w};
      f2v hx = {h.x, h.x}, hy = {h.y, h.y}, hz = {h.z, h.z}, hw = {h.w, h.w};
      aP0 = __builtin_elementwise_fma(hx, wlo, aP0);
      aQ0 = __builtin_elementwise_fma(hx, whi, aQ0);
      aP1 = __builtin_elementwise_fma(hy, wlo, aP1);
      aQ1 = __builtin_elementwise_fma(hy, whi, aQ1);
      aP2 = __builtin_elementwise_fma(hz, wlo, aP2);
      aQ2 = __builtin_elementwise_fma(hz, whi, aQ2);
      aP3 = __builtin_elementwise_fma(hw, wlo, aP3);
      aQ3 = __builtin_elementwise_fma(hw, whi, aQ3);
    }
    __syncthreads();
    if (kh == 1) {
      asum[0][u]  = aP0.x; asum[1][u]  = aP0.y; asum[2][u]  = aQ0.x; asum[3][u]  = aQ0.y;
      asum[4][u]  = aP1.x; asum[5][u]  = aP1.y; asum[6][u]  = aQ1.x; asum[7][u]  = aQ1.y;
      asum[8][u]  = aP2.x; asum[9][u]  = aP2.y; asum[10][u] = aQ2.x; asum[11][u] = aQ2.y;
      asum[12][u] = aP3.x; asum[13][u] = aP3.y; asum[14][u] = aQ3.x; asum[15][u] = aQ3.y;
    }
    __syncthreads();
    if (kh == 0) {
      aP0.x += asum[0][u];  aP0.y += asum[1][u];  aQ0.x += asum[2][u];  aQ0.y += asum[3][u];
      aP1.x += asum[4][u];  aP1.y += asum[5][u];  aQ1.x += asum[6][u];  aQ1.y += asum[7][u];
      aP2.x += asum[8][u];  aP2.y += asum[9][u];  aQ2.x += asum[10][u]; aQ2.y += asum[11][u];
      aP3.x += asum[12][u]; aP3.y += asum[13][u]; aQ3.x += asum[14][u]; aQ3.y += asum[15][u];
      if (act) {
        float4 hnew;
        {
          float gi = aP0.x + xv[0],  gf = aP0.y + xv[1],  gg = aQ0.x + xv[2],  go = aQ0.y + xv[3];
          float si = 1.f / (1.f + expf(-gi)), sf = 1.f / (1.f + expf(-gf)), so = 1.f / (1.f + expf(-go));
          c.x = sf * c.x + si * tanhf(gg);
          hnew.x = so * tanhf(c.x);
        }
        {
          float gi = aP1.x + xv[4],  gf = aP1.y + xv[5],  gg = aQ1.x + xv[6],  go = aQ1.y + xv[7];
          float si = 1.f / (1.f + expf(-gi)), sf = 1.f / (1.f + expf(-gf)), so = 1.f / (1.f + expf(-go));
          c.y = sf * c.y + si * tanhf(gg);
          hnew.y = so * tanhf(c.y);
        }
        {
          float gi = aP2.x + xv[8],  gf = aP2.y + xv[9],  gg = aQ2.x + xv[10], go = aQ2.y + xv[11];
          float si = 1.f / (1.f + expf(-gi)), sf = 1.f / (1.f + expf(-gf)), so = 1.f / (1.f + expf(-go));
          c.z = sf * c.z + si * tanhf(gg);
          hnew.z = so * tanhf(c.z);
        }
        {
          float gi = aP3.x + xv[12], gf = aP3.y + xv[13], gg = aQ3.x + xv[14], go = aQ3.y + xv[15];
          float si = 1.f / (1.f + expf(-gi)), sf = 1.f / (1.f + expf(-gf)), so = 1.f / (1.f + expf(-go));
          c.w = sf * c.w + si * tanhf(gg);
          hnew.w = so * tanhf(c.w);
        }
        hs[u] = hnew;
        size_t sb = ((size_t)i0 * 32 + t) * 250 + u;   // row stride 8000
        seq[sb]          = hnew.x;
        seq[sb + 8000]   = hnew.y;
        seq[sb + 16000]  = hnew.z;
        seq[sb + 24000]  = hnew.w;
      }
    }
    __syncthreads();
  }
}

// ---------------- init conv stage: zero xp bufs + all weight transforms -----
__global__ __launch_bounds__(256) void initconv(float4* __restrict__ zp,
                                                const float* __restrict__ c1w,
                                                const float* __restrict__ c2w,
                                                const float* __restrict__ c3w,
                                                const float* __restrict__ c4w,
                                                const float* __restrict__ c5w,
                                                u16* __restrict__ w1f, u16* __restrict__ w2f,
                                                u16* __restrict__ w3f, u16* __restrict__ w4f,
                                                u16* __restrict__ w5f) {
  const int blk = blockIdx.x;
  if (blk < 13455) {
    int i = blk * 256 + threadIdx.x;
    if (i < 3444480) zp[i] = make_float4(0.f, 0.f, 0.f, 0.f);
    return;
  }
  int e = (blk - 13455) * 256 + threadIdx.x;
  const float* src; u16* dst; int CIN, CINP, COUT, NOCG;
  if (e < 36864)        { src = c1w; dst = w1f; CIN = 12;  CINP = 32;  COUT = 128; NOCG = 8;  }
  else if (e < 258048)  { src = c2w; dst = w2f; CIN = 128; CINP = 128; COUT = 164; NOCG = 12; e -= 36864; }
  else if (e < 589824)  { src = c3w; dst = w3f; CIN = 164; CINP = 192; COUT = 192; NOCG = 12; e -= 258048; }
  else if (e < 921600)  { src = c4w; dst = w4f; CIN = 192; CINP = 192; COUT = 192; NOCG = 12; e -= 589824; }
  else if (e < 1142784) { src = c5w; dst = w5f; CIN = 192; CINP = 192; COUT = 128; NOCG = 8;  e -= 921600; }
  else return;
  int j = e & 7;
  int lane = (e >> 3) & 63;
  int fragidx = e >> 9;
  int ocg = fragidx % NOCG;
  int kg = fragidx / NOCG;
  int k = kg * 32 + (lane >> 4) * 8 + j;
  int kykx = k / CINP;
  int ic = k - kykx * CINP;
  int ky = kykx / 3, kx = kykx - ky * 3;
  int oc = ocg * 16 + (lane & 15);
  float v = 0.f;
  if (ic < CIN && oc < COUT)
    v = src[((size_t)(oc * CIN + ic) * 3 + ky) * 3 + kx];
  __hip_bfloat16 h = __float2bfloat16(v);
  dst[e] = *reinterpret_cast<u16*>(&h);
}

// ---------------- FUSED sim (12 ch, regs) + greedy (2-wave) + focus ---------
__global__ __launch_bounds__(256) void sim_fused(const float* __restrict__ seq,
                                                 const int* __restrict__ len1,
                                                 const int* __restrict__ len2,
                                                 __hip_bfloat16* __restrict__ xp1) {
  __shared__ float stg[4][32][65];    // 33,280 B (sim staging)
  __shared__ float ch9L[1024];        // 4 KB
  __shared__ float ch10L[1024];       // 4 KB
  __shared__ float maskL[1024];       // 4 KB
  __shared__ unsigned selw[64];
  const int b = blockIdx.x, tid = threadIdx.x;

  float dff[4], dbb[4], d9[4];
  float nf1[4], nb1[4], n91[4], nf2[4], nb2[4], n92[4];
#pragma unroll
  for (int pp = 0; pp < 4; pp++) {
    dff[pp] = dbb[pp] = d9[pp] = 0.f;
    nf1[pp] = nb1[pp] = n91[pp] = nf2[pp] = nb2[pp] = n92[pp] = 0.f;
  }
  for (int k0 = 0; k0 < 250; k0 += 64) {
    __syncthreads();
    for (int idx = tid; idx < 4 * 32 * 64; idx += 256) {
      int mat = idx >> 11, row = (idx >> 6) & 31, kk = idx & 63;
      int k = k0 + kk;
      stg[mat][row][kk] = (k < 250) ? seq[(size_t)((mat * 256 + b) * 32 + row) * 250 + k] : 0.f;
    }
    __syncthreads();
#pragma unroll
    for (int pp = 0; pp < 4; pp++) {
      int pr = tid + (pp << 8);
      int l = pr >> 5, m = pr & 31;
      for (int kk = 0; kk < 64; kk++) {
        float af = stg[0][l][kk], ab = stg[1][l][kk];
        float bf = stg[2][m][kk], bbv = stg[3][m][kk];
        float s1 = af + ab, s2 = bf + bbv;
        dff[pp] = fmaf(af, bf, dff[pp]);
        dbb[pp] = fmaf(ab, bbv, dbb[pp]);
        d9[pp]  = fmaf(s1, s2, d9[pp]);
        nf1[pp] = fmaf(af, af, nf1[pp]);
        nb1[pp] = fmaf(ab, ab, nb1[pp]);
        n91[pp] = fmaf(s1, s1, n91[pp]);
        nf2[pp] = fmaf(bf, bf, nf2[pp]);
        nb2[pp] = fmaf(bbv, bbv, nb2[pp]);
        n92[pp] = fmaf(s2, s2, n92[pp]);
      }
    }
  }
  const int L1 = len1[b], L2 = len2[b];
  float sv[12][4];
  bool padf[4];
#pragma unroll
  for (int pp = 0; pp < 4; pp++) {
    int pr = tid + (pp << 8);
    int l = pr >> 5, m = pr & 31;
    padf[pp] = (l >= L1 || m >= L2);
    float padv = padf[pp] ? NEGV : 0.f;
    float dcat = dff[pp] + dbb[pp];
    float n1c = nf1[pp] + nb1[pp], n2c = nf2[pp] + nb2[pp];
    sv[0][pp]  = dcat + padv;
    sv[1][pp]  = dcat / (sqrtf(n1c) * sqrtf(n2c) + 1e-8f) + padv;
    sv[2][pp]  = sqrtf(fmaxf(n1c + n2c - 2.f * dcat, 1e-12f)) + padv;
    sv[3][pp]  = dff[pp] + padv;
    sv[4][pp]  = dff[pp] / (sqrtf(nf1[pp]) * sqrtf(nf2[pp]) + 1e-8f) + padv;
    sv[5][pp]  = sqrtf(fmaxf(nf1[pp] + nf2[pp] - 2.f * dff[pp], 1e-12f)) + padv;
    sv[6][pp]  = dbb[pp] + padv;
    sv[7][pp]  = dbb[pp] / (sqrtf(nb1[pp]) * sqrtf(nb2[pp]) + 1e-8f) + padv;
    sv[8][pp]  = sqrtf(fmaxf(nb1[pp] + nb2[pp] - 2.f * dbb[pp], 1e-12f)) + padv;
    sv[9][pp]  = d9[pp] + padv;
    sv[10][pp] = d9[pp] / (sqrtf(n91[pp]) * sqrtf(n92[pp]) + 1e-8f) + padv;
    sv[11][pp] = sqrtf(fmaxf(n91[pp] + n92[pp] - 2.f * d9[pp], 1e-12f)) + padv;
    ch9L[pr]  = sv[9][pp];
    ch10L[pr] = sv[10][pp];
  }
  __syncthreads();

  unsigned sel = 0;
  if (tid < 128) {
    const int lane = tid & 63;
    const float* mm = (tid >> 6) ? ch10L : ch9L;
    float v[16];
#pragma unroll
    for (int q = 0; q < 16; q++) v[q] = mm[lane + (q << 6)];
#pragma unroll 1
    for (int it = 0; it < 32; it++) {
      float bv = v[0]; int bi = lane;
#pragma unroll
      for (int q = 1; q < 16; q++) {
        int idx = lane + (q << 6);
        if (v[q] > bv) { bv = v[q]; bi = idx; }
      }
#pragma unroll
      for (int off = 32; off > 0; off >>= 1) {
        float ov = __shfl_xor(bv, off);
        int oi = __shfl_xor(bi, off);
        if (ov > bv || (ov == bv && oi < bi)) { bv = ov; bi = oi; }
      }
      if (bv < -5000.0f) break;
      int rr = bi >> 5, cc = bi & 31;
#pragma unroll
      for (int q = 0; q < 16; q++) {
        int idx = lane + (q << 6);
        int ri = idx >> 5, ci = idx & 31;
        if (idx == bi) sel |= (1u << q);
        if (ri == rr || ci == cc) v[q] = NEGV;
      }
    }
  }
  if (tid >= 64 && tid < 128) selw[tid - 64] = sel;
  __syncthreads();
  if (tid < 64) {
    unsigned su = sel | selw[tid];
#pragma unroll
    for (int q = 0; q < 16; q++)
      maskL[tid + (q << 6)] = ((su >> q) & 1u) ? 1.0f : 0.1f;
  }
  __syncthreads();

#pragma unroll
  for (int pp = 0; pp < 4; pp++) {
    int pr = tid + (pp << 8);
    int y = pr >> 5, x = pr & 31;
    float mv = padf[pp] ? 0.f : maskL[pr];
    __hip_bfloat16* o = xp1 + ((size_t)(b * 34 + 1 + y) * 34 + 1 + x) * 32;
#pragma unroll
    for (int ch = 0; ch < 12; ch++)
      o[ch] = __float2bfloat16(sv[ch][pp] * mv);
  }
}

// ---------------- MFMA conv3x3(SAME)+bias+relu+pool2, implicit GEMM ----------
__device__ __forceinline__ int fsw(int u) { return (u ^ (u >> 2)) & 3; }

template<int S, int CINP, int GI, int TY, int COUTP_NEXT, bool LAST>
__global__ __launch_bounds__(256) void convk(const u16* __restrict__ in,
                                             const u16* __restrict__ wf,
                                             const float* __restrict__ bias,
                                             void* __restrict__ outv,
                                             int COUT, int NOCG) {
  constexpr int YR = S / TY;
  constexpr int SRX = S + 2, SRY = YR + 2;
  constexpr int PSTG = GI * SRY * SRX;
  constexpr int NCH = CINP / 32;
  constexpr int SN = S / 2;
  __shared__ u16 lds[PSTG * 32];

  const int tid = threadIdx.x;
  const int lane = tid & 63, w = tid >> 6;
  const int g = lane >> 4, li = lane & 15;
  const int bx = blockIdx.x;
  const int img0 = (bx / TY) * GI;
  const int ytile = bx - (bx / TY) * TY;
  const int ocbase = blockIdx.y * 64;

  int pbase[4], xsv[4];
#pragma unroll
  for (int f = 0; f < 4; f++) {
    int m = w * 64 + f * 16 + li;
    int gi_ = m / (YR * S);
    int yl = (m / S) % YR;
    int xl = m % S;
    pbase[f] = gi_ * (SRY * SRX) + yl * SRX + xl;
    xsv[f] = xl;
  }

  f4v acc[4][4];
#pragma unroll
  for (int f = 0; f < 4; f++)
#pragma unroll
    for (int n = 0; n < 4; n++) acc[f][n] = (f4v){0.f, 0.f, 0.f, 0.f};

  for (int c0 = 0; c0 < NCH; c0++) {
    __syncthreads();
    const int P4 = PSTG * 4;
    for (int T = tid; T < P4; T += 256) {
      int p = T >> 2, s = T & 3;
      int gi_ = p / (SRY * SRX);
      int rem = p - gi_ * (SRY * SRX);
      int yp = rem / SRX;
      int xp = rem - yp * SRX;
      int gch = s ^ fsw(xp);
      size_t soff = ((size_t)((img0 + gi_) * (S + 2) + (ytile * YR + yp)) * (S + 2) + xp) * CINP
                    + c0 * 32 + gch * 8;
      uint4 v = *(const uint4*)(in + soff);
      *(uint4*)&lds[p * 32 + s * 8] = v;
    }
    __syncthreads();
#pragma unroll
    for (int kykx = 0; kykx < 9; kykx++) {
      const int ky = kykx / 3, kx = kykx - ky * 3;
      const int kg = kykx * NCH + c0;
      s8v bfr[4];
#pragma unroll
      for (int n = 0; n < 4; n++) {
        size_t boff = ((size_t)(kg * NOCG + (ocbase >> 4) + n) * 64 + lane) * 8;
        bfr[n] = *(const s8v*)(wf + boff);
      }
      s8v afr[4];
#pragma unroll
      for (int f = 0; f < 4; f++) {
        int p = pbase[f] + ky * SRX + kx;
        int slot = g ^ fsw(xsv[f] + kx);
        afr[f] = *(const s8v*)&lds[p * 32 + slot * 8];
      }
#pragma unroll
      for (int f = 0; f < 4; f++)
#pragma unroll
        for (int n = 0; n < 4; n++)
          acc[f][n] = __builtin_amdgcn_mfma_f32_16x16x32_bf16(afr[f], bfr[n], acc[f][n], 0, 0, 0);
    }
  }

  float bia[4];
#pragma unroll
  for (int n = 0; n < 4; n++) {
    int oc = ocbase + n * 16 + li;
    bia[n] = (oc < COUT) ? bias[oc] : 0.f;
  }
  auto emit = [&](int b, int py, int px, int n, float v) {
    int oc = ocbase + n * 16 + li;
    if (oc < COUT) {
      float r = fmaxf(v + bia[n], 0.f);
      if constexpr (LAST) {
        ((float*)outv)[(size_t)b * 128 + oc] = r;
      } else {
        ((__hip_bfloat16*)outv)[((size_t)(b * (SN + 2) + 1 + py) * (SN + 2) + 1 + px) * COUTP_NEXT + oc]
            = __float2bfloat16(r);
      }
    }
  };
#pragma unroll
  for (int n = 0; n < 4; n++) {
    if constexpr (S == 32) {
#pragma unroll
      for (int p2 = 0; p2 < 2; p2++)
#pragma unroll
        for (int c = 0; c < 2; c++) {
          float v = fmaxf(fmaxf(acc[p2][n][2 * c], acc[p2][n][2 * c + 1]),
                          fmaxf(acc[p2 + 2][n][2 * c], acc[p2 + 2][n][2 * c + 1]));
          emit(img0, ytile * 4 + w, p2 * 8 + g * 2 + c, n, v);
        }
    } else if constexpr (S == 16) {
#pragma unroll
      for (int p2 = 0; p2 < 2; p2++)
#pragma unroll
        for (int c = 0; c < 2; c++) {
          float v = fmaxf(fmaxf(acc[2 * p2][n][2 * c], acc[2 * p2][n][2 * c + 1]),
                          fmaxf(acc[2 * p2 + 1][n][2 * c], acc[2 * p2 + 1][n][2 * c + 1]));
          emit(img0, w * 2 + p2, g * 2 + c, n, v);
        }
    } else if constexpr (S == 8) {
#pragma unroll
      for (int f = 0; f < 4; f++) {
        float h0 = fmaxf(acc[f][n][0], acc[f][n][1]);
        float h1 = fmaxf(acc[f][n][2], acc[f][n][3]);
        float v0 = fmaxf(h0, __shfl_xor(h0, 32));
        float v1 = fmaxf(h1, __shfl_xor(h1, 32));
        if (g < 2) {
          int px0 = (g & 1) * 2;
          emit(img0 + w, f, px0, n, v0);
          emit(img0 + w, f, px0 + 1, n, v1);
        }
      }
    } else {  // S == 4
#pragma unroll
      for (int f = 0; f < 4; f++) {
        float h0 = fmaxf(acc[f][n][0], acc[f][n][1]);
        float h1 = fmaxf(acc[f][n][2], acc[f][n][3]);
        float v0 = fmaxf(h0, __shfl_xor(h0, 16));
        float v1 = fmaxf(h1, __shfl_xor(h1, 16));
        if (!(g & 1)) {
          emit(img0 + w * 4 + f, g >> 1, 0, n, v0);
          emit(img0 + w * 4 + f, g >> 1, 1, n, v1);
        }
      }
    }
  }
}

// ---------------- FUSED conv5 (2x2 SAME + pool-final) + dense head ----------
__global__ __launch_bounds__(256) void conv5_dense(const u16* __restrict__ xp5,
                                                   const u16* __restrict__ w5f,
                                                   const float* __restrict__ c5b,
                                                   const float* __restrict__ dnn_w,
                                                   const float* __restrict__ dnn_b,
                                                   const float* __restrict__ out_w,
                                                   const float* __restrict__ out_b,
                                                   float* __restrict__ out) {
  __shared__ u16 xs[3072];        // [4][4][192] bf16 (halo-padded img)
  __shared__ float ys[128];
  __shared__ float hsd[128];
  __shared__ float lg[8];
  const int b = blockIdx.x, tid = threadIdx.x;
  const int lane = tid & 63, w = tid >> 6;
  const int li = lane & 15, g = lane >> 4;

  for (int i = tid; i < 1536; i += 256)
    ((unsigned*)xs)[i] = ((const unsigned*)(xp5 + (size_t)b * 3072))[i];
  __syncthreads();

  const int row = li & 3;
  const int y0 = 1 + (row >> 1), x0 = 1 + (row & 1);

  f4v acc0 = (f4v){0.f, 0.f, 0.f, 0.f}, acc1 = acc0;
#pragma unroll 1
  for (int kg = 0; kg < 54; kg++) {
    int k = kg * 32 + g * 8;
    int kykx = k / 192, ic = k - kykx * 192;
    int ky = kykx / 3, kx = kykx - ky * 3;
    int yy = y0 + ky - 1, xx = x0 + kx - 1;
    s8v a = *(const s8v*)&xs[(yy * 4 + xx) * 192 + ic];
    s8v b0 = *(const s8v*)(w5f + ((size_t)(kg * 8 + w * 2 + 0) * 64 + lane) * 8);
    s8v b1 = *(const s8v*)(w5f + ((size_t)(kg * 8 + w * 2 + 1) * 64 + lane) * 8);
    acc0 = __builtin_amdgcn_mfma_f32_16x16x32_bf16(a, b0, acc0, 0, 0, 0);
    acc1 = __builtin_amdgcn_mfma_f32_16x16x32_bf16(a, b1, acc1, 0, 0, 0);
  }
  if (g == 0) {
    int oc0 = (w * 2 + 0) * 16 + li;
    int oc1 = (w * 2 + 1) * 16 + li;
    float m0 = fmaxf(fmaxf(acc0[0], acc0[1]), fmaxf(acc0[2], acc0[3]));
    float m1 = fmaxf(fmaxf(acc1[0], acc1[1]), fmaxf(acc1[2], acc1[3]));
    ys[oc0] = fmaxf(m0 + c5b[oc0], 0.f);
    ys[oc1] = fmaxf(m1 + c5b[oc1], 0.f);
  }
  __syncthreads();
  if (tid < 128) {
    float acc = dnn_b[tid];
    for (int k = 0; k < 128; k++) acc = fmaf(ys[k], dnn_w[tid * 128 + k], acc);
    hsd[tid] = fmaxf(acc, 0.f);
  }
  __syncthreads();
  if (tid < 5) {
    float l = out_b[tid];
    for (int k = 0; k < 128; k++) l = fmaf(hsd[k], out_w[tid * 128 + k], l);
    lg[tid] = l;
  }
  __syncthreads();
  if (tid < 5) {
    float m = lg[0];
    for (int c = 1; c < 5; c++) m = fmaxf(m, lg[c]);
    float ssum = 0.f;
    for (int c = 0; c < 5; c++) ssum += expf(lg[c] - m);
    out[(size_t)b * 5 + tid] = lg[tid] - m - logf(ssum);
  }
}

// ---------------------------------------------------------------------------
extern "C" void kernel_launch(void* const* d_in, const int* in_sizes, int n_in,
                              void* d_out, int out_size, void* d_ws, size_t ws_size,
                              hipStream_t stream) {
  (void)in_sizes; (void)n_in; (void)out_size; (void)ws_size;
  const float* sent1 = (const float*)d_in[0];
  const float* sent2 = (const float*)d_in[1];
  const int*   len1  = (const int*)d_in[2];
  const int*   len2  = (const int*)d_in[3];
  const float* Wih   = (const float*)d_in[4];
  const float* Whh   = (const float*)d_in[5];
  const float* bih   = (const float*)d_in[6];
  const float* bhh   = (const float*)d_in[7];
  const float* c1w = (const float*)d_in[8];  const float* c1b = (const float*)d_in[9];
  const float* c2w = (const float*)d_in[10]; const float* c2b = (const float*)d_in[11];
  const float* c3w = (const float*)d_in[12]; const float* c3b = (const float*)d_in[13];
  const float* c4w = (const float*)d_in[14]; const float* c4b = (const float*)d_in[15];
  const float* c5w = (const float*)d_in[16]; const float* c5b = (const float*)d_in[17];
  const float* dnn_w = (const float*)d_in[18]; const float* dnn_b = (const float*)d_in[19];
  const float* out_w = (const float*)d_in[20]; const float* out_b = (const float*)d_in[21];
  float* out = (float*)d_out;
  float* ws = (float*)d_ws;

  // -------- workspace layout (float offsets) --------
  u16* Afh     = (u16*)(ws);               // 5,242,880 halves = 2,621,440 f
  u16* Afl     = (u16*)(ws + 2621440);     // ends 5,242,880
  u16* wihf    = (u16*)(ws + 5242880);     // 655,360 halves -> ends 5,570,560
  float* xW    = ws + 5570560;             // 16,384,000 -> ends 21,954,560
  float* seq   = ws + 21954560;            //  8,192,000 -> ends 30,146,560
  float4* Wg4  = (float4*)(ws + 30146560); //    250,000 -> ends 30,396,560
  // conv stage (reuses Afh/Afl/xW region, all dead by then):
  __hip_bfloat16* xp1 = (__hip_bfloat16*)(ws);            // [256][34][34][32]
  __hip_bfloat16* xp2 = (__hip_bfloat16*)(ws + 4733952);  // [256][18][18][128]
  __hip_bfloat16* xp3 = (__hip_bfloat16*)(ws + 10042368); // [256][10][10][192]
  __hip_bfloat16* xp4 = (__hip_bfloat16*)(ws + 12499968); // [256][6][6][192]
  __hip_bfloat16* xp5 = (__hip_bfloat16*)(ws + 13384704); // [256][4][4][192]
  // conv weight frags (inside dead xW region, below live seq):
  u16* w1f = (u16*)(ws + 21299200);
  u16* w2f = (u16*)(ws + 21317632);
  u16* w3f = (u16*)(ws + 21428224);
  u16* w4f = (u16*)(ws + 21594112);
  u16* w5f = (u16*)(ws + 21760000);

  prep_all<<<2037, 256, 0, stream>>>(sent1, sent2, Wih, Whh, Afh, Afl, wihf, Wg4);
  gemm_xw_mfma<<<dim3(64, 16), 256, 0, stream>>>(Afh, Afl, wihf, bih, bhh, xW);
  lstm_persist2p<<<256, 512, 0, stream>>>(Wg4, xW, seq);

  // zero conv bufs + all weight transforms (xW/Afh/Afl dead after lstm/gemm)
  initconv<<<17919, 256, 0, stream>>>((float4*)ws, c1w, c2w, c3w, c4w, c5w,
                                      w1f, w2f, w3f, w4f, w5f);

  sim_fused<<<256, 256, 0, stream>>>(seq, len1, len2, xp1);

  //            S   CINP GI  TY  CPN   LAST
  convk<32,  32,  1, 4, 128, false><<<dim3(1024, 2), 256, 0, stream>>>((const u16*)xp1, w1f, c1b, xp2, 128, 8);
  convk<16, 128,  1, 1, 192, false><<<dim3(256, 3), 256, 0, stream>>>((const u16*)xp2, w2f, c2b, xp3, 164, 12);
  convk< 8, 192,  4, 1, 192, false><<<dim3(64, 3), 256, 0, stream>>>((const u16*)xp3, w3f, c3b, xp4, 192, 12);
  convk< 4, 192, 16, 1, 192, false><<<dim3(16, 3), 256, 0, stream>>>((const u16*)xp4, w4f, c4b, xp5, 192, 12);

  conv5_dense<<<256, 256, 0, stream>>>((const u16*)xp5, w5f, c5b,
                                       dnn_w, dnn_b, out_w, out_b, out);
}

// Round 17
// 665.948 us; speedup vs baseline: 1.0077x; 1.0077x over previous
//
#include <hip/hip_runtime.h>
#include <hip/hip_bf16.h>
#include <hip/hip_fp16.h>
#include <math.h>

// ---------------------------------------------------------------------------
// VDPWI forward. gemm_xw via fp16 hi/lo 3-term MFMA (frag-linear A), fp32
// LSTM (persistent v2 - proven optimum, 2-barrier), fused sim+greedy+focus,
// bf16 MFMA convs, fused conv5+dense. B=256, L=32, D=300, H=250, NLAB=5.
// ---------------------------------------------------------------------------

#define NEGV (-10000.0f)

typedef unsigned short u16;
typedef __attribute__((ext_vector_type(8))) short s8v;       // 8 bf16
typedef __attribute__((ext_vector_type(8))) _Float16 h8v;    // 8 fp16
typedef __attribute__((ext_vector_type(4))) float f4v;

// ---------------- prep: transpose_hl + wih_frag + repack_whh ----------------
__global__ __launch_bounds__(256) void prep_all(const float* __restrict__ sent1,
                                                const float* __restrict__ sent2,
                                                const float* __restrict__ Wih,
                                                const float* __restrict__ Whh,
                                                u16* __restrict__ Afh,
                                                u16* __restrict__ Afl,
                                                u16* __restrict__ wihf,
                                                float4* __restrict__ Wg4) {
  __shared__ float lds[300 * 33];
  const int blk = blockIdx.x;
  if (blk < 512) {
    int s = blk >> 8, b = blk & 255;
    const float* in = (s ? sent2 : sent1) + (size_t)b * 9600;   // [300][32]
    for (int idx = threadIdx.x; idx < 9600; idx += 256) {
      int d = idx >> 5, tt = idx & 31;
      lds[d * 33 + tt] = in[idx];
    }
    __syncthreads();
    for (int odx = threadIdx.x; odx < 32 * 320; odx += 256) {
      int tt = odx / 320, d = odx - (odx / 320) * 320;
      float v = (d < 300) ? lds[d * 33 + tt] : 0.f;
      _Float16 hi = (_Float16)v;
      _Float16 lo = (_Float16)(v - (float)hi);
      int i = (s << 13) + (tt << 8) + b;
      int rowblk = i >> 4, li = i & 15;
      int kg = d >> 5, g = (d & 31) >> 3, e = d & 7;
      size_t o = (((size_t)rowblk * 10 + kg) * 64 + (g * 16 + li)) * 8 + e;
      union { _Float16 f; u16 u; } c0, c1;
      c0.f = hi; c1.f = lo;
      Afh[o] = c0.u;
      Afl[o] = c1.u;
    }
  } else if (blk < 1792) {
    int id = (blk - 512) * 256 + threadIdx.x;     // < 327680
    if (id < 327680) {
      int e    = id & 7;
      int lane = (id >> 3) & 63;
      int nf   = (id >> 9) & 63;
      int kg   = id >> 15;
      int j = nf * 16 + (lane & 15);
      int k = kg * 32 + (lane >> 4) * 8 + e;
      float v = 0.f;
      if (j < 1000 && k < 300) v = Wih[(size_t)j * 300 + k];
      _Float16 hi = (_Float16)v;
      _Float16 lo = (_Float16)(v - (float)hi);
      size_t base = (((size_t)kg * 64 + nf) * 2 * 64 + lane) * 8 + e;
      union { _Float16 f; u16 u; } c0, c1;
      c0.f = hi; c1.f = lo;
      wihf[base]       = c0.u;
      wihf[base + 512] = c1.u;
    }
  } else {
    int idx = (blk - 1792) * 256 + threadIdx.x;   // k*250 + u < 62500
    if (idx < 62500) {
      int k = idx / 250, u = idx - k * 250;
      float4 v;
      v.x = Whh[(size_t)(u)       * 250 + k];
      v.y = Whh[(size_t)(250 + u) * 250 + k];
      v.z = Whh[(size_t)(500 + u) * 250 + k];
      v.w = Whh[(size_t)(750 + u) * 250 + k];
      Wg4[idx] = v;
    }
  }
}

// ---------------- xW GEMM via MFMA: [16384x320]x[320x1024] + bias ----------
__global__ __launch_bounds__(256) void gemm_xw_mfma(const u16* __restrict__ Afh,
                                                    const u16* __restrict__ Afl,
                                                    const u16* __restrict__ bf,
                                                    const float* __restrict__ bih,
                                                    const float* __restrict__ bhh,
                                                    float* __restrict__ xW) {
  const int tid = threadIdx.x;
  const int lane = tid & 63, w = tid >> 6;
  const int li = lane & 15, g = lane >> 4;
  const int i0 = blockIdx.x * 256;
  const int j0 = blockIdx.y * 64;
  const int rb0 = (i0 >> 4) + w * 4;          // rowblk base for this wave

  f4v acc[4][4];
#pragma unroll
  for (int f = 0; f < 4; f++)
#pragma unroll
    for (int n = 0; n < 4; n++) acc[f][n] = (f4v){0.f, 0.f, 0.f, 0.f};

#pragma unroll 1
  for (int kg = 0; kg < 10; kg++) {
    h8v ah[4], al[4];
#pragma unroll
    for (int f = 0; f < 4; f++) {
      size_t aoff = (((size_t)(rb0 + f) * 10 + kg) * 64 + lane) * 8;
      ah[f] = *(const h8v*)(Afh + aoff);
      al[f] = *(const h8v*)(Afl + aoff);
    }
    h8v bh[4], bl[4];
#pragma unroll
    for (int n = 0; n < 4; n++) {
      size_t boff = (((size_t)kg * 64 + (j0 >> 4) + n) * 2 * 64 + lane) * 8;
      bh[n] = *(const h8v*)(bf + boff);
      bl[n] = *(const h8v*)(bf + boff + 512);
    }
#pragma unroll
    for (int f = 0; f < 4; f++)
#pragma unroll
      for (int n = 0; n < 4; n++) {
        acc[f][n] = __builtin_amdgcn_mfma_f32_16x16x32_f16(ah[f], bh[n], acc[f][n], 0, 0, 0);
        acc[f][n] = __builtin_amdgcn_mfma_f32_16x16x32_f16(ah[f], bl[n], acc[f][n], 0, 0, 0);
        acc[f][n] = __builtin_amdgcn_mfma_f32_16x16x32_f16(al[f], bh[n], acc[f][n], 0, 0, 0);
      }
  }

  float bia[4];
#pragma unroll
  for (int n = 0; n < 4; n++) {
    int j = j0 + n * 16 + li;
    bia[n] = (j < 1000) ? (bih[j] + bhh[j]) : 0.f;
  }
#pragma unroll
  for (int f = 0; f < 4; f++)
#pragma unroll
    for (int n = 0; n < 4; n++) {
      int j = j0 + n * 16 + li;
      if (j < 1000) {
#pragma unroll
        for (int r = 0; r < 4; r++) {
          int i = i0 + w * 64 + f * 16 + g * 4 + r;
          xW[(size_t)i * 1000 + j] = acc[f][n][r] + bia[n];
        }
      }
    }
}

// ---------------- persistent LSTM v2 (proven 384us), 2 barriers/step -------
__global__ __launch_bounds__(512, 1) void lstm_persist2(const float4* __restrict__ Wg4,
                                                        const float* __restrict__ xW,
                                                        float* __restrict__ seq) {
  __shared__ float4 hs[256];
  __shared__ float asum[16][256];
  const int tid = threadIdx.x;
  const int u = tid & 255;
  const int kh = tid >> 8;
  const bool act = (u < 250);
  const int uu = act ? u : 249;
  const int i0 = blockIdx.x * 4;
  const int lset = i0 >> 8;
  const int s = lset >> 1, dir = lset & 1;

  float4 c = make_float4(0.f, 0.f, 0.f, 0.f);
  if (tid < 256) hs[tid] = make_float4(0.f, 0.f, 0.f, 0.f);
  __syncthreads();

  const float4* wp = Wg4 + uu;
  const int k0 = kh * 125;

  for (int t = 0; t < 32; t++) {
    const int tin = dir ? (31 - t) : t;

    float xv[16];
    if (kh == 0) {
      const float* xb = xW + ((size_t)(s * 32 + tin) * 256 + (i0 & 255)) * 1000 + uu;
#pragma unroll
      for (int r = 0; r < 4; r++)
#pragma unroll
        for (int q = 0; q < 4; q++)
          xv[r * 4 + q] = xb[r * 1000 + q * 250];
    }

    float4 a0 = {0.f,0.f,0.f,0.f}, a1 = a0, a2 = a0, a3 = a0;
#pragma unroll 5
    for (int k = k0; k < k0 + 125; k++) {
      float4 w = wp[(size_t)k * 250];
      float4 h = hs[k];
      a0.x = fmaf(h.x, w.x, a0.x); a0.y = fmaf(h.x, w.y, a0.y);
      a0.z = fmaf(h.x, w.z, a0.z); a0.w = fmaf(h.x, w.w, a0.w);
      a1.x = fmaf(h.y, w.x, a1.x); a1.y = fmaf(h.y, w.y, a1.y);
      a1.z = fmaf(h.y, w.z, a1.z); a1.w = fmaf(h.y, w.w, a1.w);
      a2.x = fmaf(h.z, w.x, a2.x); a2.y = fmaf(h.z, w.y, a2.y);
      a2.z = fmaf(h.z, w.z, a2.z); a2.w = fmaf(h.z, w.w, a2.w);
      a3.x = fmaf(h.w, w.x, a3.x); a3.y = fmaf(h.w, w.y, a3.y);
      a3.z = fmaf(h.w, w.z, a3.z); a3.w = fmaf(h.w, w.w, a3.w);
    }
    // kh==1 dumps partials immediately (asum untouched by k-loop; B1 below
    // orders dump before kh==0's read AND all k-loop hs reads before hs write)
    if (kh == 1) {
      asum[0][u]  = a0.x; asum[1][u]  = a0.y; asum[2][u]  = a0.z; asum[3][u]  = a0.w;
      asum[4][u]  = a1.x; asum[5][u]  = a1.y; asum[6][u]  = a1.z; asum[7][u]  = a1.w;
      asum[8][u]  = a2.x; asum[9][u]  = a2.y; asum[10][u] = a2.z; asum[11][u] = a2.w;
      asum[12][u] = a3.x; asum[13][u] = a3.y; asum[14][u] = a3.z; asum[15][u] = a3.w;
    }
    __syncthreads();   // B1
    if (kh == 0) {
      a0.x += asum[0][u];  a0.y += asum[1][u];  a0.z += asum[2][u];  a0.w += asum[3][u];
      a1.x += asum[4][u];  a1.y += asum[5][u];  a1.z += asum[6][u];  a1.w += asum[7][u];
      a2.x += asum[8][u];  a2.y += asum[9][u];  a2.z += asum[10][u]; a2.w += asum[11][u];
      a3.x += asum[12][u]; a3.y += asum[13][u]; a3.z += asum[14][u]; a3.w += asum[15][u];
      if (act) {
        float4 hnew;
        {
          float gi = a0.x + xv[0],  gf = a0.y + xv[1],  gg = a0.z + xv[2],  go = a0.w + xv[3];
          float si = 1.f / (1.f + expf(-gi)), sf = 1.f / (1.f + expf(-gf)), so = 1.f / (1.f + expf(-go));
          c.x = sf * c.x + si * tanhf(gg);
          hnew.x = so * tanhf(c.x);
        }
        {
          float gi = a1.x + xv[4],  gf = a1.y + xv[5],  gg = a1.z + xv[6],  go = a1.w + xv[7];
          float si = 1.f / (1.f + expf(-gi)), sf = 1.f / (1.f + expf(-gf)), so = 1.f / (1.f + expf(-go));
          c.y = sf * c.y + si * tanhf(gg);
          hnew.y = so * tanhf(c.y);
        }
        {
          float gi = a2.x + xv[8],  gf = a2.y + xv[9],  gg = a2.z + xv[10], go = a2.w + xv[11];
          float si = 1.f / (1.f + expf(-gi)), sf = 1.f / (1.f + expf(-gf)), so = 1.f / (1.f + expf(-go));
          c.z = sf * c.z + si * tanhf(gg);
          hnew.z = so * tanhf(c.z);
        }
        {
          float gi = a3.x + xv[12], gf = a3.y + xv[13], gg = a3.z + xv[14], go = a3.w + xv[15];
          float si = 1.f / (1.f + expf(-gi)), sf = 1.f / (1.f + expf(-gf)), so = 1.f / (1.f + expf(-go));
          c.w = sf * c.w + si * tanhf(gg);
          hnew.w = so * tanhf(c.w);
        }
        hs[u] = hnew;
        size_t sb = ((size_t)i0 * 32 + t) * 250 + u;   // row stride 8000
        seq[sb]          = hnew.x;
        seq[sb + 8000]   = hnew.y;
        seq[sb + 16000]  = hnew.z;
        seq[sb + 24000]  = hnew.w;
      }
    }
    __syncthreads();   // B2: hs(t) visible; asum free for next step's dump
  }
}

// ---------------- init conv stage: zero xp bufs + all weight transforms -----
__global__ __launch_bounds__(256) void initconv(float4* __restrict__ zp,
                                                const float* __restrict__ c1w,
                                                const float* __restrict__ c2w,
                                                const float* __restrict__ c3w,
                                                const float* __restrict__ c4w,
                                                const float* __restrict__ c5w,
                                                u16* __restrict__ w1f, u16* __restrict__ w2f,
                                                u16* __restrict__ w3f, u16* __restrict__ w4f,
                                                u16* __restrict__ w5f) {
  const int blk = blockIdx.x;
  if (blk < 13455) {
    int i = blk * 256 + threadIdx.x;
    if (i < 3444480) zp[i] = make_float4(0.f, 0.f, 0.f, 0.f);
    return;
  }
  int e = (blk - 13455) * 256 + threadIdx.x;
  const float* src; u16* dst; int CIN, CINP, COUT, NOCG;
  if (e < 36864)        { src = c1w; dst = w1f; CIN = 12;  CINP = 32;  COUT = 128; NOCG = 8;  }
  else if (e < 258048)  { src = c2w; dst = w2f; CIN = 128; CINP = 128; COUT = 164; NOCG = 12; e -= 36864; }
  else if (e < 589824)  { src = c3w; dst = w3f; CIN = 164; CINP = 192; COUT = 192; NOCG = 12; e -= 258048; }
  else if (e < 921600)  { src = c4w; dst = w4f; CIN = 192; CINP = 192; COUT = 192; NOCG = 12; e -= 589824; }
  else if (e < 1142784) { src = c5w; dst = w5f; CIN = 192; CINP = 192; COUT = 128; NOCG = 8;  e -= 921600; }
  else return;
  int j = e & 7;
  int lane = (e >> 3) & 63;
  int fragidx = e >> 9;
  int ocg = fragidx % NOCG;
  int kg = fragidx / NOCG;
  int k = kg * 32 + (lane >> 4) * 8 + j;
  int kykx = k / CINP;
  int ic = k - kykx * CINP;
  int ky = kykx / 3, kx = kykx - ky * 3;
  int oc = ocg * 16 + (lane & 15);
  float v = 0.f;
  if (ic < CIN && oc < COUT)
    v = src[((size_t)(oc * CIN + ic) * 3 + ky) * 3 + kx];
  __hip_bfloat16 h = __float2bfloat16(v);
  dst[e] = *reinterpret_cast<u16*>(&h);
}

// ---------------- FUSED sim (12 ch, regs) + greedy (2-wave) + focus ---------
__global__ __launch_bounds__(256) void sim_fused(const float* __restrict__ seq,
                                                 const int* __restrict__ len1,
                                                 const int* __restrict__ len2,
                                                 __hip_bfloat16* __restrict__ xp1) {
  __shared__ float stg[4][32][65];    // 33,280 B (sim staging)
  __shared__ float ch9L[1024];        // 4 KB
  __shared__ float ch10L[1024];       // 4 KB
  __shared__ float maskL[1024];       // 4 KB
  __shared__ unsigned selw[64];
  const int b = blockIdx.x, tid = threadIdx.x;

  float dff[4], dbb[4], d9[4];
  float nf1[4], nb1[4], n91[4], nf2[4], nb2[4], n92[4];
#pragma unroll
  for (int pp = 0; pp < 4; pp++) {
    dff[pp] = dbb[pp] = d9[pp] = 0.f;
    nf1[pp] = nb1[pp] = n91[pp] = nf2[pp] = nb2[pp] = n92[pp] = 0.f;
  }
  for (int k0 = 0; k0 < 250; k0 += 64) {
    __syncthreads();
    for (int idx = tid; idx < 4 * 32 * 64; idx += 256) {
      int mat = idx >> 11, row = (idx >> 6) & 31, kk = idx & 63;
      int k = k0 + kk;
      stg[mat][row][kk] = (k < 250) ? seq[(size_t)((mat * 256 + b) * 32 + row) * 250 + k] : 0.f;
    }
    __syncthreads();
#pragma unroll
    for (int pp = 0; pp < 4; pp++) {
      int pr = tid + (pp << 8);
      int l = pr >> 5, m = pr & 31;
      for (int kk = 0; kk < 64; kk++) {
        float af = stg[0][l][kk], ab = stg[1][l][kk];
        float bf = stg[2][m][kk], bbv = stg[3][m][kk];
        float s1 = af + ab, s2 = bf + bbv;
        dff[pp] = fmaf(af, bf, dff[pp]);
        dbb[pp] = fmaf(ab, bbv, dbb[pp]);
        d9[pp]  = fmaf(s1, s2, d9[pp]);
        nf1[pp] = fmaf(af, af, nf1[pp]);
        nb1[pp] = fmaf(ab, ab, nb1[pp]);
        n91[pp] = fmaf(s1, s1, n91[pp]);
        nf2[pp] = fmaf(bf, bf, nf2[pp]);
        nb2[pp] = fmaf(bbv, bbv, nb2[pp]);
        n92[pp] = fmaf(s2, s2, n92[pp]);
      }
    }
  }
  const int L1 = len1[b], L2 = len2[b];
  float sv[12][4];
  bool padf[4];
#pragma unroll
  for (int pp = 0; pp < 4; pp++) {
    int pr = tid + (pp << 8);
    int l = pr >> 5, m = pr & 31;
    padf[pp] = (l >= L1 || m >= L2);
    float padv = padf[pp] ? NEGV : 0.f;
    float dcat = dff[pp] + dbb[pp];
    float n1c = nf1[pp] + nb1[pp], n2c = nf2[pp] + nb2[pp];
    sv[0][pp]  = dcat + padv;
    sv[1][pp]  = dcat / (sqrtf(n1c) * sqrtf(n2c) + 1e-8f) + padv;
    sv[2][pp]  = sqrtf(fmaxf(n1c + n2c - 2.f * dcat, 1e-12f)) + padv;
    sv[3][pp]  = dff[pp] + padv;
    sv[4][pp]  = dff[pp] / (sqrtf(nf1[pp]) * sqrtf(nf2[pp]) + 1e-8f) + padv;
    sv[5][pp]  = sqrtf(fmaxf(nf1[pp] + nf2[pp] - 2.f * dff[pp], 1e-12f)) + padv;
    sv[6][pp]  = dbb[pp] + padv;
    sv[7][pp]  = dbb[pp] / (sqrtf(nb1[pp]) * sqrtf(nb2[pp]) + 1e-8f) + padv;
    sv[8][pp]  = sqrtf(fmaxf(nb1[pp] + nb2[pp] - 2.f * dbb[pp], 1e-12f)) + padv;
    sv[9][pp]  = d9[pp] + padv;
    sv[10][pp] = d9[pp] / (sqrtf(n91[pp]) * sqrtf(n92[pp]) + 1e-8f) + padv;
    sv[11][pp] = sqrtf(fmaxf(n91[pp] + n92[pp] - 2.f * d9[pp], 1e-12f)) + padv;
    ch9L[pr]  = sv[9][pp];
    ch10L[pr] = sv[10][pp];
  }
  __syncthreads();

  unsigned sel = 0;
  if (tid < 128) {
    const int lane = tid & 63;
    const float* mm = (tid >> 6) ? ch10L : ch9L;
    float v[16];
#pragma unroll
    for (int q = 0; q < 16; q++) v[q] = mm[lane + (q << 6)];
#pragma unroll 1
    for (int it = 0; it < 32; it++) {
      float bv = v[0]; int bi = lane;
#pragma unroll
      for (int q = 1; q < 16; q++) {
        int idx = lane + (q << 6);
        if (v[q] > bv) { bv = v[q]; bi = idx; }
      }
#pragma unroll
      for (int off = 32; off > 0; off >>= 1) {
        float ov = __shfl_xor(bv, off);
        int oi = __shfl_xor(bi, off);
        if (ov > bv || (ov == bv && oi < bi)) { bv = ov; bi = oi; }
      }
      if (bv < -5000.0f) break;
      int rr = bi >> 5, cc = bi & 31;
#pragma unroll
      for (int q = 0; q < 16; q++) {
        int idx = lane + (q << 6);
        int ri = idx >> 5, ci = idx & 31;
        if (idx == bi) sel |= (1u << q);
        if (ri == rr || ci == cc) v[q] = NEGV;
      }
    }
  }
  if (tid >= 64 && tid < 128) selw[tid - 64] = sel;
  __syncthreads();
  if (tid < 64) {
    unsigned su = sel | selw[tid];
#pragma unroll
    for (int q = 0; q < 16; q++)
      maskL[tid + (q << 6)] = ((su >> q) & 1u) ? 1.0f : 0.1f;
  }
  __syncthreads();

#pragma unroll
  for (int pp = 0; pp < 4; pp++) {
    int pr = tid + (pp << 8);
    int y = pr >> 5, x = pr & 31;
    float mv = padf[pp] ? 0.f : maskL[pr];
    __hip_bfloat16* o = xp1 + ((size_t)(b * 34 + 1 + y) * 34 + 1 + x) * 32;
#pragma unroll
    for (int ch = 0; ch < 12; ch++)
      o[ch] = __float2bfloat16(sv[ch][pp] * mv);
  }
}

// ---------------- MFMA conv3x3(SAME)+bias+relu+pool2, implicit GEMM ----------
__device__ __forceinline__ int fsw(int u) { return (u ^ (u >> 2)) & 3; }

template<int S, int CINP, int GI, int TY, int COUTP_NEXT, bool LAST>
__global__ __launch_bounds__(256) void convk(const u16* __restrict__ in,
                                             const u16* __restrict__ wf,
                                             const float* __restrict__ bias,
                                             void* __restrict__ outv,
                                             int COUT, int NOCG) {
  constexpr int YR = S / TY;
  constexpr int SRX = S + 2, SRY = YR + 2;
  constexpr int PSTG = GI * SRY * SRX;
  constexpr int NCH = CINP / 32;
  constexpr int SN = S / 2;
  __shared__ u16 lds[PSTG * 32];

  const int tid = threadIdx.x;
  const int lane = tid & 63, w = tid >> 6;
  const int g = lane >> 4, li = lane & 15;
  const int bx = blockIdx.x;
  const int img0 = (bx / TY) * GI;
  const int ytile = bx - (bx / TY) * TY;
  const int ocbase = blockIdx.y * 64;

  int pbase[4], xsv[4];
#pragma unroll
  for (int f = 0; f < 4; f++) {
    int m = w * 64 + f * 16 + li;
    int gi_ = m / (YR * S);
    int yl = (m / S) % YR;
    int xl = m % S;
    pbase[f] = gi_ * (SRY * SRX) + yl * SRX + xl;
    xsv[f] = xl;
  }

  f4v acc[4][4];
#pragma unroll
  for (int f = 0; f < 4; f++)
#pragma unroll
    for (int n = 0; n < 4; n++) acc[f][n] = (f4v){0.f, 0.f, 0.f, 0.f};

  for (int c0 = 0; c0 < NCH; c0++) {
    __syncthreads();
    const int P4 = PSTG * 4;
    for (int T = tid; T < P4; T += 256) {
      int p = T >> 2, s = T & 3;
      int gi_ = p / (SRY * SRX);
      int rem = p - gi_ * (SRY * SRX);
      int yp = rem / SRX;
      int xp = rem - yp * SRX;
      int gch = s ^ fsw(xp);
      size_t soff = ((size_t)((img0 + gi_) * (S + 2) + (ytile * YR + yp)) * (S + 2) + xp) * CINP
                    + c0 * 32 + gch * 8;
      uint4 v = *(const uint4*)(in + soff);
      *(uint4*)&lds[p * 32 + s * 8] = v;
    }
    __syncthreads();
#pragma unroll
    for (int kykx = 0; kykx < 9; kykx++) {
      const int ky = kykx / 3, kx = kykx - ky * 3;
      const int kg = kykx * NCH + c0;
      s8v bfr[4];
#pragma unroll
      for (int n = 0; n < 4; n++) {
        size_t boff = ((size_t)(kg * NOCG + (ocbase >> 4) + n) * 64 + lane) * 8;
        bfr[n] = *(const s8v*)(wf + boff);
      }
      s8v afr[4];
#pragma unroll
      for (int f = 0; f < 4; f++) {
        int p = pbase[f] + ky * SRX + kx;
        int slot = g ^ fsw(xsv[f] + kx);
        afr[f] = *(const s8v*)&lds[p * 32 + slot * 8];
      }
#pragma unroll
      for (int f = 0; f < 4; f++)
#pragma unroll
        for (int n = 0; n < 4; n++)
          acc[f][n] = __builtin_amdgcn_mfma_f32_16x16x32_bf16(afr[f], bfr[n], acc[f][n], 0, 0, 0);
    }
  }

  float bia[4];
#pragma unroll
  for (int n = 0; n < 4; n++) {
    int oc = ocbase + n * 16 + li;
    bia[n] = (oc < COUT) ? bias[oc] : 0.f;
  }
  auto emit = [&](int b, int py, int px, int n, float v) {
    int oc = ocbase + n * 16 + li;
    if (oc < COUT) {
      float r = fmaxf(v + bia[n], 0.f);
      if constexpr (LAST) {
        ((float*)outv)[(size_t)b * 128 + oc] = r;
      } else {
        ((__hip_bfloat16*)outv)[((size_t)(b * (SN + 2) + 1 + py) * (SN + 2) + 1 + px) * COUTP_NEXT + oc]
            = __float2bfloat16(r);
      }
    }
  };
#pragma unroll
  for (int n = 0; n < 4; n++) {
    if constexpr (S == 32) {
#pragma unroll
      for (int p2 = 0; p2 < 2; p2++)
#pragma unroll
        for (int c = 0; c < 2; c++) {
          float v = fmaxf(fmaxf(acc[p2][n][2 * c], acc[p2][n][2 * c + 1]),
                          fmaxf(acc[p2 + 2][n][2 * c], acc[p2 + 2][n][2 * c + 1]));
          emit(img0, ytile * 4 + w, p2 * 8 + g * 2 + c, n, v);
        }
    } else if constexpr (S == 16) {
#pragma unroll
      for (int p2 = 0; p2 < 2; p2++)
#pragma unroll
        for (int c = 0; c < 2; c++) {
          float v = fmaxf(fmaxf(acc[2 * p2][n][2 * c], acc[2 * p2][n][2 * c + 1]),
                          fmaxf(acc[2 * p2 + 1][n][2 * c], acc[2 * p2 + 1][n][2 * c + 1]));
          emit(img0, w * 2 + p2, g * 2 + c, n, v);
        }
    } else if constexpr (S == 8) {
#pragma unroll
      for (int f = 0; f < 4; f++) {
        float h0 = fmaxf(acc[f][n][0], acc[f][n][1]);
        float h1 = fmaxf(acc[f][n][2], acc[f][n][3]);
        float v0 = fmaxf(h0, __shfl_xor(h0, 32));
        float v1 = fmaxf(h1, __shfl_xor(h1, 32));
        if (g < 2) {
          int px0 = (g & 1) * 2;
          emit(img0 + w, f, px0, n, v0);
          emit(img0 + w, f, px0 + 1, n, v1);
        }
      }
    } else {  // S == 4
#pragma unroll
      for (int f = 0; f < 4; f++) {
        float h0 = fmaxf(acc[f][n][0], acc[f][n][1]);
        float h1 = fmaxf(acc[f][n][2], acc[f][n][3]);
        float v0 = fmaxf(h0, __shfl_xor(h0, 16));
        float v1 = fmaxf(h1, __shfl_xor(h1, 16));
        if (!(g & 1)) {
          emit(img0 + w * 4 + f, g >> 1, 0, n, v0);
          emit(img0 + w * 4 + f, g >> 1, 1, n, v1);
        }
      }
    }
  }
}

// ---------------- FUSED conv5 (2x2 SAME + pool-final) + dense head ----------
__global__ __launch_bounds__(256) void conv5_dense(const u16* __restrict__ xp5,
                                                   const u16* __restrict__ w5f,
                                                   const float* __restrict__ c5b,
                                                   const float* __restrict__ dnn_w,
                                                   const float* __restrict__ dnn_b,
                                                   const float* __restrict__ out_w,
                                                   const float* __restrict__ out_b,
                                                   float* __restrict__ out) {
  __shared__ u16 xs[3072];        // [4][4][192] bf16 (halo-padded img)
  __shared__ float ys[128];
  __shared__ float hsd[128];
  __shared__ float lg[8];
  const int b = blockIdx.x, tid = threadIdx.x;
  const int lane = tid & 63, w = tid >> 6;
  const int li = lane & 15, g = lane >> 4;

  for (int i = tid; i < 1536; i += 256)
    ((unsigned*)xs)[i] = ((const unsigned*)(xp5 + (size_t)b * 3072))[i];
  __syncthreads();

  const int row = li & 3;
  const int y0 = 1 + (row >> 1), x0 = 1 + (row & 1);

  f4v acc0 = (f4v){0.f, 0.f, 0.f, 0.f}, acc1 = acc0;
#pragma unroll 1
  for (int kg = 0; kg < 54; kg++) {
    int k = kg * 32 + g * 8;
    int kykx = k / 192, ic = k - kykx * 192;
    int ky = kykx / 3, kx = kykx - ky * 3;
    int yy = y0 + ky - 1, xx = x0 + kx - 1;
    s8v a = *(const s8v*)&xs[(yy * 4 + xx) * 192 + ic];
    s8v b0 = *(const s8v*)(w5f + ((size_t)(kg * 8 + w * 2 + 0) * 64 + lane) * 8);
    s8v b1 = *(const s8v*)(w5f + ((size_t)(kg * 8 + w * 2 + 1) * 64 + lane) * 8);
    acc0 = __builtin_amdgcn_mfma_f32_16x16x32_bf16(a, b0, acc0, 0, 0, 0);
    acc1 = __builtin_amdgcn_mfma_f32_16x16x32_bf16(a, b1, acc1, 0, 0, 0);
  }
  if (g == 0) {
    int oc0 = (w * 2 + 0) * 16 + li;
    int oc1 = (w * 2 + 1) * 16 + li;
    float m0 = fmaxf(fmaxf(acc0[0], acc0[1]), fmaxf(acc0[2], acc0[3]));
    float m1 = fmaxf(fmaxf(acc1[0], acc1[1]), fmaxf(acc1[2], acc1[3]));
    ys[oc0] = fmaxf(m0 + c5b[oc0], 0.f);
    ys[oc1] = fmaxf(m1 + c5b[oc1], 0.f);
  }
  __syncthreads();
  if (tid < 128) {
    float acc = dnn_b[tid];
    for (int k = 0; k < 128; k++) acc = fmaf(ys[k], dnn_w[tid * 128 + k], acc);
    hsd[tid] = fmaxf(acc, 0.f);
  }
  __syncthreads();
  if (tid < 5) {
    float l = out_b[tid];
    for (int k = 0; k < 128; k++) l = fmaf(hsd[k], out_w[tid * 128 + k], l);
    lg[tid] = l;
  }
  __syncthreads();
  if (tid < 5) {
    float m = lg[0];
    for (int c = 1; c < 5; c++) m = fmaxf(m, lg[c]);
    float ssum = 0.f;
    for (int c = 0; c < 5; c++) ssum += expf(lg[c] - m);
    out[(size_t)b * 5 + tid] = lg[tid] - m - logf(ssum);
  }
}

// ---------------------------------------------------------------------------
extern "C" void kernel_launch(void* const* d_in, const int* in_sizes, int n_in,
                              void* d_out, int out_size, void* d_ws, size_t ws_size,
                              hipStream_t stream) {
  (void)in_sizes; (void)n_in; (void)out_size; (void)ws_size;
  const float* sent1 = (const float*)d_in[0];
  const float* sent2 = (const float*)d_in[1];
  const int*   len1  = (const int*)d_in[2];
  const int*   len2  = (const int*)d_in[3];
  const float* Wih   = (const float*)d_in[4];
  const float* Whh   = (const float*)d_in[5];
  const float* bih   = (const float*)d_in[6];
  const float* bhh   = (const float*)d_in[7];
  const float* c1w = (const float*)d_in[8];  const float* c1b = (const float*)d_in[9];
  const float* c2w = (const float*)d_in[10]; const float* c2b = (const float*)d_in[11];
  const float* c3w = (const float*)d_in[12]; const float* c3b = (const float*)d_in[13];
  const float* c4w = (const float*)d_in[14]; const float* c4b = (const float*)d_in[15];
  const float* c5w = (const float*)d_in[16]; const float* c5b = (const float*)d_in[17];
  const float* dnn_w = (const float*)d_in[18]; const float* dnn_b = (const float*)d_in[19];
  const float* out_w = (const float*)d_in[20]; const float* out_b = (const float*)d_in[21];
  float* out = (float*)d_out;
  float* ws = (float*)d_ws;

  // -------- workspace layout (float offsets) --------
  u16* Afh     = (u16*)(ws);               // 5,242,880 halves = 2,621,440 f
  u16* Afl     = (u16*)(ws + 2621440);     // ends 5,242,880
  u16* wihf    = (u16*)(ws + 5242880);     // 655,360 halves -> ends 5,570,560
  float* xW    = ws + 5570560;             // 16,384,000 -> ends 21,954,560
  float* seq   = ws + 21954560;            //  8,192,000 -> ends 30,146,560
  float4* Wg4  = (float4*)(ws + 30146560); //    250,000 -> ends 30,396,560
  // conv stage (reuses Afh/Afl/xW region, all dead by then):
  __hip_bfloat16* xp1 = (__hip_bfloat16*)(ws);            // [256][34][34][32]
  __hip_bfloat16* xp2 = (__hip_bfloat16*)(ws + 4733952);  // [256][18][18][128]
  __hip_bfloat16* xp3 = (__hip_bfloat16*)(ws + 10042368); // [256][10][10][192]
  __hip_bfloat16* xp4 = (__hip_bfloat16*)(ws + 12499968); // [256][6][6][192]
  __hip_bfloat16* xp5 = (__hip_bfloat16*)(ws + 13384704); // [256][4][4][192]
  // conv weight frags (inside dead xW region, below live seq):
  u16* w1f = (u16*)(ws + 21299200);
  u16* w2f = (u16*)(ws + 21317632);
  u16* w3f = (u16*)(ws + 21428224);
  u16* w4f = (u16*)(ws + 21594112);
  u16* w5f = (u16*)(ws + 21760000);

  prep_all<<<2037, 256, 0, stream>>>(sent1, sent2, Wih, Whh, Afh, Afl, wihf, Wg4);
  gemm_xw_mfma<<<dim3(64, 16), 256, 0, stream>>>(Afh, Afl, wihf, bih, bhh, xW);
  lstm_persist2<<<256, 512, 0, stream>>>(Wg4, xW, seq);

  // zero conv bufs + all weight transforms (xW/Afh/Afl dead after lstm/gemm)
  initconv<<<17919, 256, 0, stream>>>((float4*)ws, c1w, c2w, c3w, c4w, c5w,
                                      w1f, w2f, w3f, w4f, w5f);

  sim_fused<<<256, 256, 0, stream>>>(seq, len1, len2, xp1);

  //            S   CINP GI  TY  CPN   LAST
  convk<32,  32,  1, 4, 128, false><<<dim3(1024, 2), 256, 0, stream>>>((const u16*)xp1, w1f, c1b, xp2, 128, 8);
  convk<16, 128,  1, 1, 192, false><<<dim3(256, 3), 256, 0, stream>>>((const u16*)xp2, w2f, c2b, xp3, 164, 12);
  convk< 8, 192,  4, 1, 192, false><<<dim3(64, 3), 256, 0, stream>>>((const u16*)xp3, w3f, c3b, xp4, 192, 12);
  convk< 4, 192, 16, 1, 192, false><<<dim3(16, 3), 256, 0, stream>>>((const u16*)xp4, w4f, c4b, xp5, 192, 12);

  conv5_dense<<<256, 256, 0, stream>>>((const u16*)xp5, w5f, c5b,
                                       dnn_w, dnn_b, out_w, out_b, out);
}